// Round 2
// baseline (93.049 us; speedup 1.0000x reference)
//
#include <hip/hip_runtime.h>

// LocalConvolutionMixMerge: per-pixel local conv, 3x3 + 5x5, weights shared
// across 8 channel groups (c % 32).
//
// Layout: one thread per (n, wc, h, w); wave = one full image row (w=0..63),
// so horizontal stencil neighbors come from DPP wave shifts (zero-fill at the
// wave edge == the image's zero padding in w). Vertical neighbors are 5
// row loads per channel group. Weights (read-once) and outputs (write-once)
// use non-temporal accesses so L1 keeps the reused x rows.

#define HW_ 4096

__device__ __forceinline__ float dpp_shl1(float v) {  // D[i] = S[i+1]; lane63 -> 0
  return __builtin_bit_cast(
      float, __builtin_amdgcn_update_dpp(0, __builtin_bit_cast(int, v),
                                         0x130, 0xF, 0xF, true));
}
__device__ __forceinline__ float dpp_shr1(float v) {  // D[i] = S[i-1]; lane0 -> 0
  return __builtin_bit_cast(
      float, __builtin_amdgcn_update_dpp(0, __builtin_bit_cast(int, v),
                                         0x138, 0xF, 0xF, true));
}

__global__ __launch_bounds__(256) void lconv_mix_kernel(
    const float* __restrict__ x, const float* __restrict__ wgt,
    float* __restrict__ out) {
  int idx = blockIdx.x * blockDim.x + threadIdx.x;  // 2*32*64*64 = 262144
  int w  = idx & 63;
  int h  = (idx >> 6) & 63;
  int wc = (idx >> 12) & 31;
  int n  = idx >> 17;

  const float* wbase = wgt + (size_t)n * 1088 * HW_ + h * 64 + w;
  float w1[9], w2[25];
#pragma unroll
  for (int t = 0; t < 9; ++t)
    w1[t] = __builtin_nontemporal_load(&wbase[(size_t)(wc * 9 + t) * HW_]);
#pragma unroll
  for (int t = 0; t < 25; ++t)
    w2[t] = __builtin_nontemporal_load(&wbase[(size_t)(288 + wc * 25 + t) * HW_]);

  const float* xn = x + (size_t)n * 256 * HW_ + h * 64 + w;
  float* o1 = out + ((size_t)(n * 2 + 0) * 256) * HW_ + h * 64 + w;
  float* o2 = out + ((size_t)(n * 2 + 1) * 256) * HW_ + h * 64 + w;

#pragma unroll
  for (int g = 0; g < 8; ++g) {
    int cc = g * 32 + wc;
    const float* xc = xn + (size_t)cc * HW_;

    // 5 vertical taps at this thread's own column (wave-uniform predicate).
    float r[5];
#pragma unroll
    for (int i = 0; i < 5; ++i) {
      int hh = h + i - 2;
      r[i] = ((unsigned)hh < 64u) ? xc[(i - 2) * 64] : 0.0f;
    }

    float a1 = 0.0f, a2 = 0.0f;
#pragma unroll
    for (int i = 0; i < 5; ++i) {
      float m1 = dpp_shr1(r[i]);   // value at w-1 (0 at w==0)
      float m2 = dpp_shr1(m1);     // value at w-2
      float q1 = dpp_shl1(r[i]);   // value at w+1 (0 at w==63)
      float q2 = dpp_shl1(q1);     // value at w+2

      a2 = fmaf(m2,   w2[i * 5 + 0], a2);
      a2 = fmaf(m1,   w2[i * 5 + 1], a2);
      a2 = fmaf(r[i], w2[i * 5 + 2], a2);
      a2 = fmaf(q1,   w2[i * 5 + 3], a2);
      a2 = fmaf(q2,   w2[i * 5 + 4], a2);

      if (i >= 1 && i <= 3) {  // inner 3x3 reuses the same shifted values
        a1 = fmaf(m1,   w1[(i - 1) * 3 + 0], a1);
        a1 = fmaf(r[i], w1[(i - 1) * 3 + 1], a1);
        a1 = fmaf(q1,   w1[(i - 1) * 3 + 2], a1);
      }
    }

    __builtin_nontemporal_store(a1, &o1[(size_t)cc * HW_]);
    __builtin_nontemporal_store(a2, &o2[(size_t)cc * HW_]);
  }
}

extern "C" void kernel_launch(void* const* d_in, const int* in_sizes, int n_in,
                              void* d_out, int out_size, void* d_ws,
                              size_t ws_size, hipStream_t stream) {
  const float* x = (const float*)d_in[0];
  const float* wgt = (const float*)d_in[1];
  float* out = (float*)d_out;

  int total = 2 * 32 * 64 * 64;  // N * WC * H * W
  lconv_mix_kernel<<<dim3(total / 256), dim3(256), 0, stream>>>(x, wgt, out);
}